// Round 5
// baseline (3320.716 us; speedup 1.0000x reference)
//
#include <hip/hip_runtime.h>
#include <hip/hip_bf16.h>
#include <math.h>

#define N_NODES 65536
#define IN_DIM  128
#define HID     256
#define OUT_DIM 128
#define G4      512   // 4*OUT
#define N_EDGES 1048576
#define BATCH   64
#define SEQ_T   1024  // N_NODES / BATCH

// ---------------- workspace layout (bytes) ----------------
// Small arrays, then two big ping-pong regions (liveness-checked):
//   R1 (128MB): agg0 -> agg1 -> xbuf(layer0) -> xbuf(layer1)
//   R2 ( 64MB): h0   -> D    -> ys0
static constexpr size_t OFF_CNT   = 0x000000;                  // N*4 = 256KB
static constexpr size_t OFF_ROW   = 0x040000;                  // 256KB
static constexpr size_t OFF_CUR   = 0x080000;                  // 256KB
static constexpr size_t OFF_DINV  = 0x0C0000;                  // 256KB
static constexpr size_t OFF_BSUM  = 0x100000;                  // 4KB (scan sums + dtype flag)
static constexpr size_t OFF_COL   = 0x101000;                  // E*4 = 4MB
static constexpr size_t OFF_ENORM = 0x501000;                  // E*4 = 4MB  (ends 0x901000)
static constexpr size_t OFF_R1    = 0xA00000;                  // 128MB
static constexpr size_t OFF_R2    = OFF_R1 + 0x8000000;        // 64MB
static constexpr size_t WS_NEED   = OFF_R2 + 0x4000000;        // 0xCA00000 ~= 202MB

// ---------------- ws-shortfall sentinel: uniform 1e30 output ----------------
// Distinguishes "workspace too small" from any real indexing/numerics bug.
__global__ void k_sentinel(float* __restrict__ out, int n) {
    int i = blockIdx.x * blockDim.x + threadIdx.x;
    if (i < n) out[i] = 1e30f;
}

// ---------------- edge dtype detection (int32 vs int64, device-side) ----------------
// If edge_index is little-endian int64 with values in [0, 2^31), every odd 32-bit
// word (the hi half) is 0. If int32, odd words are random node ids (~0 w.p. 1/65536).
__global__ void k_detect(const unsigned* __restrict__ ei32, int* __restrict__ flag) {
    int t = threadIdx.x;
    unsigned v = ei32[2 * t + 1] | ei32[2 * (t + 977) + 1] | ei32[2 * (t + 300000) + 1];
    unsigned long long ball = __ballot(v != 0u);
    if (t == 0) *flag = (ball == 0ull) ? 1 : 0;  // 1 = int64
}

__device__ __forceinline__ int edge_at(const int* ei32, const long long* ei64,
                                       int is64, int idx) {
    return is64 ? (int)ei64[idx] : ei32[idx];
}

// ---------------- prep kernels ----------------
__global__ void k_zero2(int* __restrict__ a, int* __restrict__ b) {
    int i = blockIdx.x * blockDim.x + threadIdx.x;
    if (i < N_NODES) { a[i] = 0; b[i] = 0; }
}

__global__ void k_count(const int* __restrict__ ei32, const long long* __restrict__ ei64,
                        const int* __restrict__ flag, int* __restrict__ cnt) {
    int e = blockIdx.x * blockDim.x + threadIdx.x;
    int is64 = *flag;
    if (e < N_EDGES) {
        int d = edge_at(ei32, ei64, is64, N_EDGES + e);
        atomicAdd(&cnt[d], 1);
    }
}

__global__ void k_dinv(const int* __restrict__ cnt, float* __restrict__ dinv) {
    int n = blockIdx.x * blockDim.x + threadIdx.x;
    if (n < N_NODES) dinv[n] = rsqrtf((float)(cnt[n] + 1));  // +1 self loop
}

__global__ void k_scan_block(const int* __restrict__ cnt, int* __restrict__ row_ptr,
                             int* __restrict__ bsum) {
    __shared__ int s[256];
    int i = blockIdx.x * 256 + threadIdx.x;
    int v = cnt[i];
    s[threadIdx.x] = v;
    __syncthreads();
    for (int off = 1; off < 256; off <<= 1) {
        int t = (threadIdx.x >= off) ? s[threadIdx.x - off] : 0;
        __syncthreads();
        s[threadIdx.x] += t;
        __syncthreads();
    }
    row_ptr[i] = s[threadIdx.x] - v;  // exclusive within block
    if (threadIdx.x == 255) bsum[blockIdx.x] = s[255];
}

__global__ void k_scan_bsum(int* __restrict__ bsum) {
    __shared__ int s[256];
    int v = bsum[threadIdx.x];
    s[threadIdx.x] = v;
    __syncthreads();
    for (int off = 1; off < 256; off <<= 1) {
        int t = (threadIdx.x >= off) ? s[threadIdx.x - off] : 0;
        __syncthreads();
        s[threadIdx.x] += t;
        __syncthreads();
    }
    bsum[threadIdx.x] = s[threadIdx.x] - v;  // exclusive
}

__global__ void k_scan_add(int* __restrict__ row_ptr, const int* __restrict__ bsum) {
    int i = blockIdx.x * 256 + threadIdx.x;
    row_ptr[i] += bsum[blockIdx.x];
}

__global__ void k_scatter(const int* __restrict__ ei32, const long long* __restrict__ ei64,
                          const int* __restrict__ flag, const int* __restrict__ row_ptr,
                          int* __restrict__ cursor, const float* __restrict__ dinv,
                          int* __restrict__ col, float* __restrict__ enorm) {
    int e = blockIdx.x * blockDim.x + threadIdx.x;
    int is64 = *flag;
    if (e < N_EDGES) {
        int s = edge_at(ei32, ei64, is64, e);
        int d = edge_at(ei32, ei64, is64, N_EDGES + e);
        int slot = row_ptr[d] + atomicAdd(&cursor[d], 1);
        col[slot]   = s;
        enorm[slot] = dinv[s] * dinv[d];
    }
}

// ---------------- aggregation: one wave per node ----------------
template <int DIM>
__launch_bounds__(256)
__global__ void k_aggregate(const float* __restrict__ x, const int* __restrict__ row_ptr,
                            const int* __restrict__ cnt, const int* __restrict__ col,
                            const float* __restrict__ enorm, const float* __restrict__ dinv,
                            float* __restrict__ outb) {
    constexpr int VEC = DIM / 64;
    int gw   = (blockIdx.x * 256 + threadIdx.x) >> 6;
    int lane = threadIdx.x & 63;
    if (gw >= N_NODES) return;

    float dn = dinv[gw];
    float sw = dn * dn;  // self-loop norm
    float acc0 = 0.f, acc1 = 0.f, acc2 = 0.f, acc3 = 0.f;
    if constexpr (VEC == 2) {
        float2 t = *(const float2*)(x + (size_t)gw * DIM + lane * 2);
        acc0 = t.x * sw; acc1 = t.y * sw;
    } else {
        float4 t = *(const float4*)(x + (size_t)gw * DIM + lane * 4);
        acc0 = t.x * sw; acc1 = t.y * sw; acc2 = t.z * sw; acc3 = t.w * sw;
    }

    int base = row_ptr[gw], len = cnt[gw];
    for (int off = 0; off < len; off += 64) {
        int rem = len - off;
        int c_  = 0;
        float w_ = 0.f;
        if (lane < rem) {
            c_ = col[base + off + lane];
            w_ = enorm[base + off + lane];
        }
        int m = rem < 64 ? rem : 64;
        for (int j = 0; j < m; j++) {
            int   sj = __shfl(c_, j);
            float wj = __shfl(w_, j);
            const float* xs = x + (size_t)sj * DIM;
            if constexpr (VEC == 2) {
                float2 t = *(const float2*)(xs + lane * 2);
                acc0 += t.x * wj; acc1 += t.y * wj;
            } else {
                float4 t = *(const float4*)(xs + lane * 4);
                acc0 += t.x * wj; acc1 += t.y * wj; acc2 += t.z * wj; acc3 += t.w * wj;
            }
        }
    }
    float* orow = outb + (size_t)gw * DIM;
    if constexpr (VEC == 2) {
        *(float2*)(orow + lane * 2) = make_float2(acc0, acc1);
    } else {
        *(float4*)(orow + lane * 4) = make_float4(acc0, acc1, acc2, acc3);
    }
}

// ---------------- generic f32 GEMM: C[M][Nfull] = A[M][K] @ B + bias ----------------
// BT=false: B is [K][Nfull] row-major.  BT=true: B = W[Nfull][K] row-major, used transposed.
// EPI: 0 = +bias, 1 = +bias,relu, 2 = +bias+bias2
template <int K, bool BT, int EPI>
__launch_bounds__(256)
__global__ void k_gemm(const float* __restrict__ A, const float* __restrict__ Bm,
                       const float* __restrict__ bias, const float* __restrict__ bias2,
                       float* __restrict__ C, int Nfull) {
    constexpr int BM = 128, BN = 128, BK = 16;
    __shared__ __align__(16) float As[BK][BM + 4];
    __shared__ __align__(16) float Bs[BK][BN + 4];
    int tid = threadIdx.x;
    int m0 = blockIdx.x * BM, n0 = blockIdx.y * BN;
    int tr = tid >> 4, tc = tid & 15;

    float acc[8][8];
#pragma unroll
    for (int i = 0; i < 8; i++)
#pragma unroll
        for (int j = 0; j < 8; j++) acc[i][j] = 0.f;

    int lkq = tid & 3;    // k-quad for strided loads
    int lm  = tid >> 2;   // 0..63
    int lnq = tid & 31;   // n-quad for BT=false B loads
    int lkk = tid >> 5;   // 0..7

    for (int k0 = 0; k0 < K; k0 += BK) {
#pragma unroll
        for (int p = 0; p < 2; p++) {
            int m = lm + p * 64;
            float4 a4 = *(const float4*)(A + (size_t)(m0 + m) * K + k0 + lkq * 4);
            As[lkq * 4 + 0][m] = a4.x;
            As[lkq * 4 + 1][m] = a4.y;
            As[lkq * 4 + 2][m] = a4.z;
            As[lkq * 4 + 3][m] = a4.w;
        }
        if constexpr (!BT) {
#pragma unroll
            for (int p = 0; p < 2; p++) {
                int kk = lkk + p * 8;
                float4 b4 = *(const float4*)(Bm + (size_t)(k0 + kk) * Nfull + n0 + lnq * 4);
                *(float4*)&Bs[kk][lnq * 4] = b4;
            }
        } else {
#pragma unroll
            for (int p = 0; p < 2; p++) {
                int n = lm + p * 64;
                float4 b4 = *(const float4*)(Bm + (size_t)(n0 + n) * K + k0 + lkq * 4);
                Bs[lkq * 4 + 0][n] = b4.x;
                Bs[lkq * 4 + 1][n] = b4.y;
                Bs[lkq * 4 + 2][n] = b4.z;
                Bs[lkq * 4 + 3][n] = b4.w;
            }
        }
        __syncthreads();
#pragma unroll
        for (int k = 0; k < BK; k++) {
            float4 aa0 = *(const float4*)&As[k][tr * 8];
            float4 aa1 = *(const float4*)&As[k][tr * 8 + 4];
            float4 bb0 = *(const float4*)&Bs[k][tc * 8];
            float4 bb1 = *(const float4*)&Bs[k][tc * 8 + 4];
            float av[8] = {aa0.x, aa0.y, aa0.z, aa0.w, aa1.x, aa1.y, aa1.z, aa1.w};
            float bv[8] = {bb0.x, bb0.y, bb0.z, bb0.w, bb1.x, bb1.y, bb1.z, bb1.w};
#pragma unroll
            for (int i = 0; i < 8; i++)
#pragma unroll
                for (int j = 0; j < 8; j++) acc[i][j] += av[i] * bv[j];
        }
        __syncthreads();
    }

    float bz[8];
#pragma unroll
    for (int j = 0; j < 8; j++) {
        int cc = n0 + tc * 8 + j;
        float b = bias[cc];
        if constexpr (EPI == 2) b += bias2[cc];
        bz[j] = b;
    }
#pragma unroll
    for (int i = 0; i < 8; i++) {
        int row = m0 + tr * 8 + i;
        float vv[8];
#pragma unroll
        for (int j = 0; j < 8; j++) {
            float v = acc[i][j] + bz[j];
            if constexpr (EPI == 1) v = fmaxf(v, 0.f);
            vv[j] = v;
        }
        float* orow = C + (size_t)row * Nfull + n0 + tc * 8;
        *(float4*)orow       = make_float4(vv[0], vv[1], vv[2], vv[3]);
        *(float4*)(orow + 4) = make_float4(vv[4], vv[5], vv[6], vv[7]);
    }
}

// ---------------- GEMM1 + bias + LayerNorm, output rows permuted to [t][b] ----------------
__launch_bounds__(256)
__global__ void k_gemm_ln(const float* __restrict__ A, const float* __restrict__ W1,
                          const float* __restrict__ b1, const float* __restrict__ gamma,
                          const float* __restrict__ beta, float* __restrict__ D) {
    constexpr int BM = 64, BK = 16;
    __shared__ __align__(16) float As[BK][BM + 4];
    __shared__ __align__(16) float Bs[BK][HID + 4];
    int tid = threadIdx.x;
    int m0 = blockIdx.x * BM;
    int tr = tid >> 5, tc = tid & 31;  // 8 x 32 threads, each 8x8 outputs

    float acc[8][8];
#pragma unroll
    for (int i = 0; i < 8; i++)
#pragma unroll
        for (int j = 0; j < 8; j++) acc[i][j] = 0.f;

    int lkq = tid & 3, lm = tid >> 2;    // A loads
    int lnq = tid & 63, lkk = tid >> 6;  // B loads

    for (int k0 = 0; k0 < HID; k0 += BK) {
        {
            float4 a4 = *(const float4*)(A + (size_t)(m0 + lm) * HID + k0 + lkq * 4);
            As[lkq * 4 + 0][lm] = a4.x;
            As[lkq * 4 + 1][lm] = a4.y;
            As[lkq * 4 + 2][lm] = a4.z;
            As[lkq * 4 + 3][lm] = a4.w;
        }
#pragma unroll
        for (int p = 0; p < 4; p++) {
            int kk = lkk + p * 4;
            float4 b4 = *(const float4*)(W1 + (size_t)(k0 + kk) * HID + lnq * 4);
            *(float4*)&Bs[kk][lnq * 4] = b4;
        }
        __syncthreads();
#pragma unroll
        for (int k = 0; k < BK; k++) {
            float4 aa0 = *(const float4*)&As[k][tr * 8];
            float4 aa1 = *(const float4*)&As[k][tr * 8 + 4];
            float4 bb0 = *(const float4*)&Bs[k][tc * 8];
            float4 bb1 = *(const float4*)&Bs[k][tc * 8 + 4];
            float av[8] = {aa0.x, aa0.y, aa0.z, aa0.w, aa1.x, aa1.y, aa1.z, aa1.w};
            float bv[8] = {bb0.x, bb0.y, bb0.z, bb0.w, bb1.x, bb1.y, bb1.z, bb1.w};
#pragma unroll
            for (int i = 0; i < 8; i++)
#pragma unroll
                for (int j = 0; j < 8; j++) acc[i][j] += av[i] * bv[j];
        }
        __syncthreads();
    }

    float vv[8][8];
    float rs[8], rq[8];
#pragma unroll
    for (int i = 0; i < 8; i++) { rs[i] = 0.f; rq[i] = 0.f; }
#pragma unroll
    for (int j = 0; j < 8; j++) {
        float bb = b1[tc * 8 + j];
#pragma unroll
        for (int i = 0; i < 8; i++) {
            float v = acc[i][j] + bb;
            vv[i][j] = v;
            rs[i] += v;
            rq[i] += v * v;
        }
    }
#pragma unroll
    for (int m = 1; m < 32; m <<= 1) {
#pragma unroll
        for (int i = 0; i < 8; i++) {
            rs[i] += __shfl_xor(rs[i], m, 32);
            rq[i] += __shfl_xor(rq[i], m, 32);
        }
    }
    float gm[8], bt[8];
#pragma unroll
    for (int j = 0; j < 8; j++) {
        gm[j] = gamma[tc * 8 + j];
        bt[j] = beta[tc * 8 + j];
    }
#pragma unroll
    for (int i = 0; i < 8; i++) {
        float mean = rs[i] * (1.f / 256.f);
        float var  = rq[i] * (1.f / 256.f) - mean * mean;
        float rstd = rsqrtf(var + 1e-5f);
        int n = m0 + tr * 8 + i;
        int orow = ((n & (SEQ_T - 1)) << 6) | (n >> 10);  // t*64 + b
        float o[8];
#pragma unroll
        for (int j = 0; j < 8; j++) o[j] = (vv[i][j] - mean) * rstd * gm[j] + bt[j];
        float* op = D + (size_t)orow * HID + tc * 8;
        *(float4*)op       = make_float4(o[0], o[1], o[2], o[3]);
        *(float4*)(op + 4) = make_float4(o[4], o[5], o[6], o[7]);
    }
}

// ---------------- LSTM recurrence: one workgroup per sequence ----------------
__device__ __forceinline__ float sigmf(float x) { return 1.f / (1.f + __expf(-x)); }
__device__ __forceinline__ float tanhft(float x) {
    float t = __expf(-2.f * fabsf(x));
    float r = (1.f - t) / (1.f + t);
    return copysignf(r, x);
}
__device__ __forceinline__ float dot4(float4 a, float4 b) {
    return a.x * b.x + a.y * b.y + a.z * b.z + a.w * b.w;
}

template <int LAYER>
__launch_bounds__(512)
__global__ void k_lstm(const float* __restrict__ Whh, const float* __restrict__ xpart,
                       float* __restrict__ ys, float* __restrict__ outp) {
    __shared__ float hbuf[128];
    __shared__ float actv[512];
    int b = blockIdx.x, tid = threadIdx.x;
    int gg = tid >> 3, kc = tid & 7;  // gate-row group (8 rows), k-chunk (16 k)

    float4 w4[8][4];
#pragma unroll
    for (int u = 0; u < 8; u++) {
        const float4* wr = (const float4*)(Whh + (size_t)(gg * 8 + u) * 128 + kc * 16);
#pragma unroll
        for (int q = 0; q < 4; q++) w4[u][q] = wr[q];
    }
    if (tid < 128) hbuf[tid] = 0.f;
    float c = 0.f;
    float xp = xpart[(size_t)b * G4 + tid];  // t = 0 row
    __syncthreads();

    for (int t = 0; t < SEQ_T; t++) {
        float4 h0 = *(const float4*)(hbuf + kc * 16);
        float4 h1 = *(const float4*)(hbuf + kc * 16 + 4);
        float4 h2 = *(const float4*)(hbuf + kc * 16 + 8);
        float4 h3 = *(const float4*)(hbuf + kc * 16 + 12);
        float acc[8];
#pragma unroll
        for (int u = 0; u < 8; u++) {
            acc[u] = dot4(w4[u][0], h0) + dot4(w4[u][1], h1) +
                     dot4(w4[u][2], h2) + dot4(w4[u][3], h3);
        }
        int tn = t + 1 < SEQ_T ? t + 1 : SEQ_T - 1;
        float xpn = xpart[((size_t)tn * BATCH + b) * G4 + tid];

#pragma unroll
        for (int u = 0; u < 8; u++) {
            acc[u] += __shfl_xor(acc[u], 1, 8);
            acc[u] += __shfl_xor(acc[u], 2, 8);
            acc[u] += __shfl_xor(acc[u], 4, 8);
        }
        float gs = acc[0];
#pragma unroll
        for (int u = 1; u < 8; u++) gs = (kc == u) ? acc[u] : gs;
        gs += xp;

        int cls = tid >> 7;  // 0:i 1:f 2:g 3:o
        float a = (cls == 2) ? tanhft(gs) : sigmf(gs);
        actv[tid] = a;
        __syncthreads();

        if (tid < 128) {
            float ai = actv[tid], af = actv[tid + 128], ag = actv[tid + 256], ao = actv[tid + 384];
            c = af * c + ai * ag;
            float hn = ao * tanhft(c);
            hbuf[tid] = hn;
            if constexpr (LAYER == 0) {
                ys[((size_t)t * BATCH + b) * OUT_DIM + tid] = hn;
            } else {
                if (t == SEQ_T - 1) outp[b * OUT_DIM + tid] = hn;
            }
        }
        xp = xpn;
        __syncthreads();
    }
}

// ---------------- launch ----------------
extern "C" void kernel_launch(void* const* d_in, const int* in_sizes, int n_in,
                              void* d_out, int out_size, void* d_ws, size_t ws_size,
                              hipStream_t stream) {
    const float*     x     = (const float*)d_in[0];
    const int*       ei32  = (const int*)d_in[1];
    const long long* ei64  = (const long long*)d_in[1];
    const float*     W0    = (const float*)d_in[3];
    const float*     b0    = (const float*)d_in[4];
    const float*     W1    = (const float*)d_in[5];
    const float*     b1    = (const float*)d_in[6];
    const float*     gamma = (const float*)d_in[7];
    const float*     beta  = (const float*)d_in[8];
    const float*     Wih0  = (const float*)d_in[9];
    const float*     Whh0  = (const float*)d_in[10];
    const float*     bih0  = (const float*)d_in[11];
    const float*     bhh0  = (const float*)d_in[12];
    const float*     Wih1  = (const float*)d_in[13];
    const float*     Whh1  = (const float*)d_in[14];
    const float*     bih1  = (const float*)d_in[15];
    const float*     bhh1  = (const float*)d_in[16];
    float* out = (float*)d_out;

    if (ws_size < WS_NEED) {
        // Workspace shortfall: emit unmistakable sentinel so the failure mode is
        // distinguishable from a numerics/indexing bug (uniform 1e30 output).
        k_sentinel<<<(out_size + 255) / 256, 256, 0, stream>>>(out, out_size);
        return;
    }

    char*  ws      = (char*)d_ws;
    int*   cnt     = (int*)(ws + OFF_CNT);
    int*   row_ptr = (int*)(ws + OFF_ROW);
    int*   cursor  = (int*)(ws + OFF_CUR);
    float* dinv    = (float*)(ws + OFF_DINV);
    int*   bsum    = (int*)(ws + OFF_BSUM);
    int*   dflag   = (int*)(ws + OFF_BSUM + 2048);
    int*   col     = (int*)(ws + OFF_COL);
    float* enorm   = (float*)(ws + OFF_ENORM);
    float* R1      = (float*)(ws + OFF_R1);  // 128MB: agg0 / agg1 / xbuf
    float* R2      = (float*)(ws + OFF_R2);  // 64MB : h0 / D / ys0

    float* agg0 = R1;
    float* h0   = R2;
    float* agg1 = R1;
    float* Dbuf = R2;
    float* xbuf = R1;
    float* ys0  = R2;

    // ---- GCN prep: dtype sniff, degrees, norm, CSR by dst ----
    k_detect<<<1, 64, 0, stream>>>((const unsigned*)d_in[1], dflag);
    k_zero2<<<256, 256, 0, stream>>>(cnt, cursor);
    k_count<<<4096, 256, 0, stream>>>(ei32, ei64, dflag, cnt);
    k_dinv<<<256, 256, 0, stream>>>(cnt, dinv);
    k_scan_block<<<256, 256, 0, stream>>>(cnt, row_ptr, bsum);
    k_scan_bsum<<<1, 256, 0, stream>>>(bsum);
    k_scan_add<<<256, 256, 0, stream>>>(row_ptr, bsum);
    k_scatter<<<4096, 256, 0, stream>>>(ei32, ei64, dflag, row_ptr, cursor, dinv, col, enorm);

    // ---- GCN layer 0: aggregate(x) @ W0 + b0, ReLU ----
    k_aggregate<IN_DIM><<<N_NODES / 4, 256, 0, stream>>>(x, row_ptr, cnt, col, enorm, dinv, agg0);
    k_gemm<IN_DIM, false, 1><<<dim3(N_NODES / 128, HID / 128), 256, 0, stream>>>(
        agg0, W0, b0, nullptr, h0, HID);

    // ---- GCN layer 1: aggregate(h0) @ W1 + b1, then LayerNorm (rows -> [t][b]) ----
    k_aggregate<HID><<<N_NODES / 4, 256, 0, stream>>>(h0, row_ptr, cnt, col, enorm, dinv, agg1);
    k_gemm_ln<<<N_NODES / 64, 256, 0, stream>>>(agg1, W1, b1, gamma, beta, Dbuf);

    // ---- LSTM layer 0 ----
    k_gemm<HID, true, 2><<<dim3(N_NODES / 128, G4 / 128), 256, 0, stream>>>(
        Dbuf, Wih0, bih0, bhh0, xbuf, G4);
    k_lstm<0><<<BATCH, 512, 0, stream>>>(Whh0, xbuf, ys0, nullptr);

    // ---- LSTM layer 1 ----
    k_gemm<OUT_DIM, true, 2><<<dim3(N_NODES / 128, G4 / 128), 256, 0, stream>>>(
        ys0, Wih1, bih1, bhh1, xbuf, G4);
    k_lstm<1><<<BATCH, 512, 0, stream>>>(Whh1, xbuf, nullptr, out);
}

// Round 8
// 2693.024 us; speedup vs baseline: 1.2331x; 1.2331x over previous
//
#include <hip/hip_runtime.h>
#include <hip/hip_bf16.h>
#include <math.h>

#define N_NODES 65536
#define IN_DIM  128
#define HID     256
#define OUT_DIM 128
#define G4      512   // 4*OUT
#define N_EDGES 1048576
#define BATCH   64
#define SEQ_T   1024  // N_NODES / BATCH

// ---------------- workspace layout (bytes) ----------------
//   R1 (128MB): agg0 -> agg1 -> xbuf(layer0) -> xbuf(layer1)
//   R2 ( 64MB): h0   -> D    -> ys0
static constexpr size_t OFF_CNT   = 0x000000;
static constexpr size_t OFF_ROW   = 0x040000;
static constexpr size_t OFF_CUR   = 0x080000;
static constexpr size_t OFF_DINV  = 0x0C0000;
static constexpr size_t OFF_BSUM  = 0x100000;
static constexpr size_t OFF_COL   = 0x101000;
static constexpr size_t OFF_ENORM = 0x501000;
static constexpr size_t OFF_R1    = 0xA00000;
static constexpr size_t OFF_R2    = OFF_R1 + 0x8000000;
static constexpr size_t WS_NEED   = OFF_R2 + 0x4000000;   // ~202MB

// ---------------- ws-shortfall sentinel ----------------
__global__ void k_sentinel(float* __restrict__ out, int n) {
    int i = blockIdx.x * blockDim.x + threadIdx.x;
    if (i < n) out[i] = 1e30f;
}

// ---------------- edge dtype detection (int32 vs int64) ----------------
__global__ void k_detect(const unsigned* __restrict__ ei32, int* __restrict__ flag) {
    int t = threadIdx.x;
    unsigned v = ei32[2 * t + 1] | ei32[2 * (t + 977) + 1] | ei32[2 * (t + 300000) + 1];
    unsigned long long ball = __ballot(v != 0u);
    if (t == 0) *flag = (ball == 0ull) ? 1 : 0;  // 1 = int64
}

__device__ __forceinline__ int edge_at(const int* ei32, const long long* ei64,
                                       int is64, int idx) {
    return is64 ? (int)ei64[idx] : ei32[idx];
}

// ---------------- prep kernels ----------------
__global__ void k_zero2(int* __restrict__ a, int* __restrict__ b) {
    int i = blockIdx.x * blockDim.x + threadIdx.x;
    if (i < N_NODES) { a[i] = 0; b[i] = 0; }
}

__global__ void k_count(const int* __restrict__ ei32, const long long* __restrict__ ei64,
                        const int* __restrict__ flag, int* __restrict__ cnt) {
    int e = blockIdx.x * blockDim.x + threadIdx.x;
    int is64 = *flag;
    if (e < N_EDGES) {
        int d = edge_at(ei32, ei64, is64, N_EDGES + e);
        atomicAdd(&cnt[d], 1);
    }
}

__global__ void k_dinv(const int* __restrict__ cnt, float* __restrict__ dinv) {
    int n = blockIdx.x * blockDim.x + threadIdx.x;
    if (n < N_NODES) dinv[n] = rsqrtf((float)(cnt[n] + 1));
}

__global__ void k_scan_block(const int* __restrict__ cnt, int* __restrict__ row_ptr,
                             int* __restrict__ bsum) {
    __shared__ int s[256];
    int i = blockIdx.x * 256 + threadIdx.x;
    int v = cnt[i];
    s[threadIdx.x] = v;
    __syncthreads();
    for (int off = 1; off < 256; off <<= 1) {
        int t = (threadIdx.x >= off) ? s[threadIdx.x - off] : 0;
        __syncthreads();
        s[threadIdx.x] += t;
        __syncthreads();
    }
    row_ptr[i] = s[threadIdx.x] - v;
    if (threadIdx.x == 255) bsum[blockIdx.x] = s[255];
}

__global__ void k_scan_bsum(int* __restrict__ bsum) {
    __shared__ int s[256];
    int v = bsum[threadIdx.x];
    s[threadIdx.x] = v;
    __syncthreads();
    for (int off = 1; off < 256; off <<= 1) {
        int t = (threadIdx.x >= off) ? s[threadIdx.x - off] : 0;
        __syncthreads();
        s[threadIdx.x] += t;
        __syncthreads();
    }
    bsum[threadIdx.x] = s[threadIdx.x] - v;
}

__global__ void k_scan_add(int* __restrict__ row_ptr, const int* __restrict__ bsum) {
    int i = blockIdx.x * 256 + threadIdx.x;
    row_ptr[i] += bsum[blockIdx.x];
}

__global__ void k_scatter(const int* __restrict__ ei32, const long long* __restrict__ ei64,
                          const int* __restrict__ flag, const int* __restrict__ row_ptr,
                          int* __restrict__ cursor, const float* __restrict__ dinv,
                          int* __restrict__ col, float* __restrict__ enorm) {
    int e = blockIdx.x * blockDim.x + threadIdx.x;
    int is64 = *flag;
    if (e < N_EDGES) {
        int s = edge_at(ei32, ei64, is64, e);
        int d = edge_at(ei32, ei64, is64, N_EDGES + e);
        int slot = row_ptr[d] + atomicAdd(&cursor[d], 1);
        col[slot]   = s;
        enorm[slot] = dinv[s] * dinv[d];
    }
}

// ---------------- aggregation: one wave per node ----------------
template <int DIM>
__launch_bounds__(256)
__global__ void k_aggregate(const float* __restrict__ x, const int* __restrict__ row_ptr,
                            const int* __restrict__ cnt, const int* __restrict__ col,
                            const float* __restrict__ enorm, const float* __restrict__ dinv,
                            float* __restrict__ outb) {
    constexpr int VEC = DIM / 64;
    int gw   = (blockIdx.x * 256 + threadIdx.x) >> 6;
    int lane = threadIdx.x & 63;
    if (gw >= N_NODES) return;

    float dn = dinv[gw];
    float sw = dn * dn;
    float acc0 = 0.f, acc1 = 0.f, acc2 = 0.f, acc3 = 0.f;
    if constexpr (VEC == 2) {
        float2 t = *(const float2*)(x + (size_t)gw * DIM + lane * 2);
        acc0 = t.x * sw; acc1 = t.y * sw;
    } else {
        float4 t = *(const float4*)(x + (size_t)gw * DIM + lane * 4);
        acc0 = t.x * sw; acc1 = t.y * sw; acc2 = t.z * sw; acc3 = t.w * sw;
    }

    int base = row_ptr[gw], len = cnt[gw];
    for (int off = 0; off < len; off += 64) {
        int rem = len - off;
        int c_  = 0;
        float w_ = 0.f;
        if (lane < rem) {
            c_ = col[base + off + lane];
            w_ = enorm[base + off + lane];
        }
        int m = rem < 64 ? rem : 64;
        for (int j = 0; j < m; j++) {
            int   sj = __shfl(c_, j);
            float wj = __shfl(w_, j);
            const float* xs = x + (size_t)sj * DIM;
            if constexpr (VEC == 2) {
                float2 t = *(const float2*)(xs + lane * 2);
                acc0 += t.x * wj; acc1 += t.y * wj;
            } else {
                float4 t = *(const float4*)(xs + lane * 4);
                acc0 += t.x * wj; acc1 += t.y * wj; acc2 += t.z * wj; acc3 += t.w * wj;
            }
        }
    }
    float* orow = outb + (size_t)gw * DIM;
    if constexpr (VEC == 2) {
        *(float2*)(orow + lane * 2) = make_float2(acc0, acc1);
    } else {
        *(float4*)(orow + lane * 4) = make_float4(acc0, acc1, acc2, acc3);
    }
}

// ---------------- generic f32 GEMM ----------------
template <int K, bool BT, int EPI>
__launch_bounds__(256)
__global__ void k_gemm(const float* __restrict__ A, const float* __restrict__ Bm,
                       const float* __restrict__ bias, const float* __restrict__ bias2,
                       float* __restrict__ C, int Nfull) {
    constexpr int BM = 128, BN = 128, BK = 16;
    __shared__ __align__(16) float As[BK][BM + 4];
    __shared__ __align__(16) float Bs[BK][BN + 4];
    int tid = threadIdx.x;
    int m0 = blockIdx.x * BM, n0 = blockIdx.y * BN;
    int tr = tid >> 4, tc = tid & 15;

    float acc[8][8];
#pragma unroll
    for (int i = 0; i < 8; i++)
#pragma unroll
        for (int j = 0; j < 8; j++) acc[i][j] = 0.f;

    int lkq = tid & 3;
    int lm  = tid >> 2;
    int lnq = tid & 31;
    int lkk = tid >> 5;

    for (int k0 = 0; k0 < K; k0 += BK) {
#pragma unroll
        for (int p = 0; p < 2; p++) {
            int m = lm + p * 64;
            float4 a4 = *(const float4*)(A + (size_t)(m0 + m) * K + k0 + lkq * 4);
            As[lkq * 4 + 0][m] = a4.x;
            As[lkq * 4 + 1][m] = a4.y;
            As[lkq * 4 + 2][m] = a4.z;
            As[lkq * 4 + 3][m] = a4.w;
        }
        if constexpr (!BT) {
#pragma unroll
            for (int p = 0; p < 2; p++) {
                int kk = lkk + p * 8;
                float4 b4 = *(const float4*)(Bm + (size_t)(k0 + kk) * Nfull + n0 + lnq * 4);
                *(float4*)&Bs[kk][lnq * 4] = b4;
            }
        } else {
#pragma unroll
            for (int p = 0; p < 2; p++) {
                int n = lm + p * 64;
                float4 b4 = *(const float4*)(Bm + (size_t)(n0 + n) * K + k0 + lkq * 4);
                Bs[lkq * 4 + 0][n] = b4.x;
                Bs[lkq * 4 + 1][n] = b4.y;
                Bs[lkq * 4 + 2][n] = b4.z;
                Bs[lkq * 4 + 3][n] = b4.w;
            }
        }
        __syncthreads();
#pragma unroll
        for (int k = 0; k < BK; k++) {
            float4 aa0 = *(const float4*)&As[k][tr * 8];
            float4 aa1 = *(const float4*)&As[k][tr * 8 + 4];
            float4 bb0 = *(const float4*)&Bs[k][tc * 8];
            float4 bb1 = *(const float4*)&Bs[k][tc * 8 + 4];
            float av[8] = {aa0.x, aa0.y, aa0.z, aa0.w, aa1.x, aa1.y, aa1.z, aa1.w};
            float bv[8] = {bb0.x, bb0.y, bb0.z, bb0.w, bb1.x, bb1.y, bb1.z, bb1.w};
#pragma unroll
            for (int i = 0; i < 8; i++)
#pragma unroll
                for (int j = 0; j < 8; j++) acc[i][j] += av[i] * bv[j];
        }
        __syncthreads();
    }

    float bz[8];
#pragma unroll
    for (int j = 0; j < 8; j++) {
        int cc = n0 + tc * 8 + j;
        float b = bias[cc];
        if constexpr (EPI == 2) b += bias2[cc];
        bz[j] = b;
    }
#pragma unroll
    for (int i = 0; i < 8; i++) {
        int row = m0 + tr * 8 + i;
        float vv[8];
#pragma unroll
        for (int j = 0; j < 8; j++) {
            float v = acc[i][j] + bz[j];
            if constexpr (EPI == 1) v = fmaxf(v, 0.f);
            vv[j] = v;
        }
        float* orow = C + (size_t)row * Nfull + n0 + tc * 8;
        *(float4*)orow       = make_float4(vv[0], vv[1], vv[2], vv[3]);
        *(float4*)(orow + 4) = make_float4(vv[4], vv[5], vv[6], vv[7]);
    }
}

// ---------------- GEMM1 + bias + LayerNorm, rows permuted to [t][b] ----------------
__launch_bounds__(256)
__global__ void k_gemm_ln(const float* __restrict__ A, const float* __restrict__ W1,
                          const float* __restrict__ b1, const float* __restrict__ gamma,
                          const float* __restrict__ beta, float* __restrict__ D) {
    constexpr int BM = 64, BK = 16;
    __shared__ __align__(16) float As[BK][BM + 4];
    __shared__ __align__(16) float Bs[BK][HID + 4];
    int tid = threadIdx.x;
    int m0 = blockIdx.x * BM;
    int tr = tid >> 5, tc = tid & 31;

    float acc[8][8];
#pragma unroll
    for (int i = 0; i < 8; i++)
#pragma unroll
        for (int j = 0; j < 8; j++) acc[i][j] = 0.f;

    int lkq = tid & 3, lm = tid >> 2;
    int lnq = tid & 63, lkk = tid >> 6;

    for (int k0 = 0; k0 < HID; k0 += BK) {
        {
            float4 a4 = *(const float4*)(A + (size_t)(m0 + lm) * HID + k0 + lkq * 4);
            As[lkq * 4 + 0][lm] = a4.x;
            As[lkq * 4 + 1][lm] = a4.y;
            As[lkq * 4 + 2][lm] = a4.z;
            As[lkq * 4 + 3][lm] = a4.w;
        }
#pragma unroll
        for (int p = 0; p < 4; p++) {
            int kk = lkk + p * 4;
            float4 b4 = *(const float4*)(W1 + (size_t)(k0 + kk) * HID + lnq * 4);
            *(float4*)&Bs[kk][lnq * 4] = b4;
        }
        __syncthreads();
#pragma unroll
        for (int k = 0; k < BK; k++) {
            float4 aa0 = *(const float4*)&As[k][tr * 8];
            float4 aa1 = *(const float4*)&As[k][tr * 8 + 4];
            float4 bb0 = *(const float4*)&Bs[k][tc * 8];
            float4 bb1 = *(const float4*)&Bs[k][tc * 8 + 4];
            float av[8] = {aa0.x, aa0.y, aa0.z, aa0.w, aa1.x, aa1.y, aa1.z, aa1.w};
            float bv[8] = {bb0.x, bb0.y, bb0.z, bb0.w, bb1.x, bb1.y, bb1.z, bb1.w};
#pragma unroll
            for (int i = 0; i < 8; i++)
#pragma unroll
                for (int j = 0; j < 8; j++) acc[i][j] += av[i] * bv[j];
        }
        __syncthreads();
    }

    float vv[8][8];
    float rs[8], rq[8];
#pragma unroll
    for (int i = 0; i < 8; i++) { rs[i] = 0.f; rq[i] = 0.f; }
#pragma unroll
    for (int j = 0; j < 8; j++) {
        float bb = b1[tc * 8 + j];
#pragma unroll
        for (int i = 0; i < 8; i++) {
            float v = acc[i][j] + bb;
            vv[i][j] = v;
            rs[i] += v;
            rq[i] += v * v;
        }
    }
#pragma unroll
    for (int m = 1; m < 32; m <<= 1) {
#pragma unroll
        for (int i = 0; i < 8; i++) {
            rs[i] += __shfl_xor(rs[i], m, 32);
            rq[i] += __shfl_xor(rq[i], m, 32);
        }
    }
    float gm[8], bt[8];
#pragma unroll
    for (int j = 0; j < 8; j++) {
        gm[j] = gamma[tc * 8 + j];
        bt[j] = beta[tc * 8 + j];
    }
#pragma unroll
    for (int i = 0; i < 8; i++) {
        float mean = rs[i] * (1.f / 256.f);
        float var  = rq[i] * (1.f / 256.f) - mean * mean;
        float rstd = rsqrtf(var + 1e-5f);
        int n = m0 + tr * 8 + i;
        int orow = ((n & (SEQ_T - 1)) << 6) | (n >> 10);  // t*64 + b
        float o[8];
#pragma unroll
        for (int j = 0; j < 8; j++) o[j] = (vv[i][j] - mean) * rstd * gm[j] + bt[j];
        float* op = D + (size_t)orow * HID + tc * 8;
        *(float4*)op       = make_float4(o[0], o[1], o[2], o[3]);
        *(float4*)(op + 4) = make_float4(o[4], o[5], o[6], o[7]);
    }
}

// ---------------- LSTM recurrence: one workgroup per sequence ----------------
// 512 threads: group gq = tid>>2 owns hidden unit gq; lane kc = tid&3 owns
// k-slice [kc*32, kc*32+32). Thread's 4 rows = gates {i,f,g,o} of unit gq.
// Width-4 allreduce -> every lane holds all 4 gate sums -> no serial tail.
// hbuf: double-buffered, 16-float chunks padded to 20 -> conflict-free b128
// (read: 4 distinct addrs/wave, 16-lane broadcast each, banks disjoint;
//  write: 16 consecutive banks). One barrier per step.
// __launch_bounds__(512,2): 256-VGPR budget keeps the 128-VGPR weight array
// register-resident (round-5 counter showed VGPR=84 => weights not resident).
__device__ __forceinline__ float tanhft(float x) {
    float t = __expf(-2.f * fabsf(x));
    float r = __fdividef(1.f - t, 1.f + t);
    return copysignf(r, x);
}

template <int LAYER>
__launch_bounds__(512, 2)
__global__ void k_lstm(const float* __restrict__ Whh, const float* __restrict__ xpart,
                       float* __restrict__ ys, float* __restrict__ outp) {
    __shared__ float hbuf[2][160];   // 8 chunks x (16 data + 4 pad)
    int b = blockIdx.x, tid = threadIdx.x;
    int gq = tid >> 2, kc = tid & 3;

    float4 w[32];
#pragma unroll
    for (int u = 0; u < 4; u++) {
        const float4* wr = (const float4*)(Whh + (size_t)(u * 128 + gq) * 128 + kc * 32);
#pragma unroll
        for (int q = 0; q < 8; q++) w[u * 8 + q] = wr[q];
    }
    if (tid < 160) { hbuf[0][tid] = 0.f; hbuf[1][tid] = 0.f; }

    float c = 0.f;
    float xq0 = xpart[(size_t)b * G4 +   0 + gq];
    float xq1 = xpart[(size_t)b * G4 + 128 + gq];
    float xq2 = xpart[(size_t)b * G4 + 256 + gq];
    float xq3 = xpart[(size_t)b * G4 + 384 + gq];
    int bs = 0;
    __syncthreads();

    for (int t = 0; t < SEQ_T; t++) {
        float4 h4[8];
#pragma unroll
        for (int q = 0; q < 8; q++) {
            int off = (2 * kc + (q >> 2)) * 20 + (q & 3) * 4;
            h4[q] = *(const float4*)&hbuf[bs][off];
        }
        int tn = t + 1 < SEQ_T ? t + 1 : SEQ_T - 1;
        const float* xr = xpart + ((size_t)tn * BATCH + b) * G4 + gq;
        float xn0 = xr[0], xn1 = xr[128], xn2 = xr[256], xn3 = xr[384];

        float2 a2[4];
#pragma unroll
        for (int u = 0; u < 4; u++) a2[u] = make_float2(0.f, 0.f);
#pragma unroll
        for (int u = 0; u < 4; u++) {
#pragma unroll
            for (int q = 0; q < 8; q++) {
                float4 wv = w[u * 8 + q];
                float4 hv = h4[q];
                a2[u].x = fmaf(wv.x, hv.x, a2[u].x);
                a2[u].y = fmaf(wv.y, hv.y, a2[u].y);
                a2[u].x = fmaf(wv.z, hv.z, a2[u].x);
                a2[u].y = fmaf(wv.w, hv.w, a2[u].y);
            }
        }
        float g0 = a2[0].x + a2[0].y, g1 = a2[1].x + a2[1].y;
        float g2 = a2[2].x + a2[2].y, g3 = a2[3].x + a2[3].y;

        g0 += __shfl_xor(g0, 1, 4); g1 += __shfl_xor(g1, 1, 4);
        g2 += __shfl_xor(g2, 1, 4); g3 += __shfl_xor(g3, 1, 4);
        g0 += __shfl_xor(g0, 2, 4); g1 += __shfl_xor(g1, 2, 4);
        g2 += __shfl_xor(g2, 2, 4); g3 += __shfl_xor(g3, 2, 4);

        g0 += xq0; g1 += xq1; g2 += xq2; g3 += xq3;

        float ei = __expf(-g0), ef = __expf(-g1), eo = __expf(-g3);
        float ai = __fdividef(1.f, 1.f + ei);
        float af = __fdividef(1.f, 1.f + ef);
        float ao = __fdividef(1.f, 1.f + eo);
        float ag = tanhft(g2);

        c = fmaf(af, c, ai * ag);
        float hn = ao * tanhft(c);

        if (kc == 0) {
            hbuf[bs ^ 1][(gq >> 4) * 20 + (gq & 15)] = hn;
            if constexpr (LAYER == 0) {
                ys[((size_t)t * BATCH + b) * OUT_DIM + gq] = hn;
            } else {
                if (t == SEQ_T - 1) outp[b * OUT_DIM + gq] = hn;
            }
        }
        xq0 = xn0; xq1 = xn1; xq2 = xn2; xq3 = xn3;
        bs ^= 1;
        __syncthreads();
    }
}

// ---------------- launch ----------------
extern "C" void kernel_launch(void* const* d_in, const int* in_sizes, int n_in,
                              void* d_out, int out_size, void* d_ws, size_t ws_size,
                              hipStream_t stream) {
    const float*     x     = (const float*)d_in[0];
    const int*       ei32  = (const int*)d_in[1];
    const long long* ei64  = (const long long*)d_in[1];
    const float*     W0    = (const float*)d_in[3];
    const float*     b0    = (const float*)d_in[4];
    const float*     W1    = (const float*)d_in[5];
    const float*     b1    = (const float*)d_in[6];
    const float*     gamma = (const float*)d_in[7];
    const float*     beta  = (const float*)d_in[8];
    const float*     Wih0  = (const float*)d_in[9];
    const float*     Whh0  = (const float*)d_in[10];
    const float*     bih0  = (const float*)d_in[11];
    const float*     bhh0  = (const float*)d_in[12];
    const float*     Wih1  = (const float*)d_in[13];
    const float*     Whh1  = (const float*)d_in[14];
    const float*     bih1  = (const float*)d_in[15];
    const float*     bhh1  = (const float*)d_in[16];
    float* out = (float*)d_out;

    if (ws_size < WS_NEED) {
        k_sentinel<<<(out_size + 255) / 256, 256, 0, stream>>>(out, out_size);
        return;
    }

    char*  ws      = (char*)d_ws;
    int*   cnt     = (int*)(ws + OFF_CNT);
    int*   row_ptr = (int*)(ws + OFF_ROW);
    int*   cursor  = (int*)(ws + OFF_CUR);
    float* dinv    = (float*)(ws + OFF_DINV);
    int*   bsum    = (int*)(ws + OFF_BSUM);
    int*   dflag   = (int*)(ws + OFF_BSUM + 2048);
    int*   col     = (int*)(ws + OFF_COL);
    float* enorm   = (float*)(ws + OFF_ENORM);
    float* R1      = (float*)(ws + OFF_R1);
    float* R2      = (float*)(ws + OFF_R2);

    float* agg0 = R1;
    float* h0   = R2;
    float* agg1 = R1;
    float* Dbuf = R2;
    float* xbuf = R1;
    float* ys0  = R2;

    // ---- GCN prep ----
    k_detect<<<1, 64, 0, stream>>>((const unsigned*)d_in[1], dflag);
    k_zero2<<<256, 256, 0, stream>>>(cnt, cursor);
    k_count<<<4096, 256, 0, stream>>>(ei32, ei64, dflag, cnt);
    k_dinv<<<256, 256, 0, stream>>>(cnt, dinv);
    k_scan_block<<<256, 256, 0, stream>>>(cnt, row_ptr, bsum);
    k_scan_bsum<<<1, 256, 0, stream>>>(bsum);
    k_scan_add<<<256, 256, 0, stream>>>(row_ptr, bsum);
    k_scatter<<<4096, 256, 0, stream>>>(ei32, ei64, dflag, row_ptr, cursor, dinv, col, enorm);

    // ---- GCN layer 0 ----
    k_aggregate<IN_DIM><<<N_NODES / 4, 256, 0, stream>>>(x, row_ptr, cnt, col, enorm, dinv, agg0);
    k_gemm<IN_DIM, false, 1><<<dim3(N_NODES / 128, HID / 128), 256, 0, stream>>>(
        agg0, W0, b0, nullptr, h0, HID);

    // ---- GCN layer 1 + LayerNorm ----
    k_aggregate<HID><<<N_NODES / 4, 256, 0, stream>>>(h0, row_ptr, cnt, col, enorm, dinv, agg1);
    k_gemm_ln<<<N_NODES / 64, 256, 0, stream>>>(agg1, W1, b1, gamma, beta, Dbuf);

    // ---- LSTM layer 0 ----
    k_gemm<HID, true, 2><<<dim3(N_NODES / 128, G4 / 128), 256, 0, stream>>>(
        Dbuf, Wih0, bih0, bhh0, xbuf, G4);
    k_lstm<0><<<BATCH, 512, 0, stream>>>(Whh0, xbuf, ys0, nullptr);

    // ---- LSTM layer 1 ----
    k_gemm<OUT_DIM, true, 2><<<dim3(N_NODES / 128, G4 / 128), 256, 0, stream>>>(
        ys0, Wih1, bih1, bhh1, xbuf, G4);
    k_lstm<1><<<BATCH, 512, 0, stream>>>(Whh1, xbuf, nullptr, out);
}